// Round 4
// baseline (495.441 us; speedup 1.0000x reference)
//
#include <hip/hip_runtime.h>
#include <hip/hip_bf16.h>
#include <math.h>

#define N_PANO 50000
#define N_FP   10000
#define HID    128
#define OUT_C  64
#define E_PP   800000
#define E_PF   50000

typedef unsigned short ushort_t;
typedef unsigned int uint_t;
typedef __attribute__((ext_vector_type(8))) short short8;
typedef __attribute__((ext_vector_type(4))) float f32x4;

static inline int cdiv(int a, int b) { return (a + b - 1) / b; }

__device__ inline ushort_t f2bf(float x) {
    __hip_bfloat16 h = __float2bfloat16(x);   // RNE
    return *reinterpret_cast<ushort_t*>(&h);
}
__device__ inline float bfu2f(ushort_t u) {
    return __uint_as_float(((uint_t)u) << 16);
}
__device__ inline uint_t pack2bf(float a, float b) {
    return (uint_t)f2bf(a) | ((uint_t)f2bf(b) << 16);
}
__device__ inline f32x4 mfma16(short8 a, short8 b, f32x4 c) {
    return __builtin_amdgcn_mfma_f32_16x16x32_bf16(a, b, c, 0, 0, 0);
}

// ---------------- CSR build ----------------
__global__ __launch_bounds__(256) void zero_i32(int* p, int n) {
    int i = blockIdx.x * 256 + threadIdx.x;
    if (i < n) p[i] = 0;
}

__global__ __launch_bounds__(256) void count_k(const int* __restrict__ dst, int E, int* __restrict__ cnt) {
    int i = blockIdx.x * 256 + threadIdx.x;
    if (i < E) atomicAdd(&cnt[dst[i]], 1);
}

__global__ __launch_bounds__(1024) void scan_local(const int* __restrict__ cnt, int* __restrict__ ptr,
                                                   int* __restrict__ bsum, int n) {
    __shared__ int wsum[16];
    int tid = threadIdx.x, lane = tid & 63, wid = tid >> 6;
    int i = blockIdx.x * 1024 + tid;
    int v = (i < n) ? cnt[i] : 0;
    int incl = v;
    #pragma unroll
    for (int off = 1; off < 64; off <<= 1) {
        int t = __shfl_up(incl, off, 64);
        if (lane >= off) incl += t;
    }
    if (lane == 63) wsum[wid] = incl;
    __syncthreads();
    if (tid == 0) {
        int run = 0;
        #pragma unroll
        for (int w = 0; w < 16; ++w) { int t = wsum[w]; wsum[w] = run; run += t; }
        bsum[blockIdx.x] = run;
    }
    __syncthreads();
    int excl = wsum[wid] + incl - v;
    if (i < n) ptr[i] = excl;
}

__global__ __launch_bounds__(64) void scan_bsum(int* __restrict__ bsum, int nb, int* __restrict__ total_out) {
    int lane = threadIdx.x;
    int v = (lane < nb) ? bsum[lane] : 0;
    int incl = v;
    #pragma unroll
    for (int off = 1; off < 64; off <<= 1) {
        int t = __shfl_up(incl, off, 64);
        if (lane >= off) incl += t;
    }
    if (lane < nb) bsum[lane] = incl - v;
    if (lane == 63) *total_out = incl;
}

__global__ __launch_bounds__(1024) void scan_add(int* __restrict__ ptr, int* __restrict__ cur,
                                                 const int* __restrict__ bsum, int n) {
    int i = blockIdx.x * 1024 + threadIdx.x;
    if (i < n) {
        int v = ptr[i] + bsum[blockIdx.x];
        ptr[i] = v;
        cur[i] = v;
    }
}

__global__ __launch_bounds__(256) void scatter_k(const int* __restrict__ src, const int* __restrict__ dst,
                                                 int E, int* __restrict__ cur, int* __restrict__ col) {
    int i = blockIdx.x * 256 + threadIdx.x;
    if (i < E) {
        int p = atomicAdd(&cur[dst[i]], 1);
        col[p] = src[i];
    }
}

// ---------------- wed[i] = sum_j W[i][j]*a[j] ----------------
__global__ __launch_bounds__(64) void wed_wave(const float* __restrict__ W, const float* __restrict__ a,
                                               float* __restrict__ o, int C) {
    int r = blockIdx.x, lane = threadIdx.x;
    float s = 0.f;
    for (int j = lane; j < C; j += 64) s += W[r * C + j] * a[j];
    #pragma unroll
    for (int off = 32; off; off >>= 1) s += __shfl_down(s, off, 64);
    if (lane == 0) o[r] = s;
}

// ---------------- weight transpose + bf16 hi/lo split ----------------
// W[k][C] row-major -> WT_h/WT_l [n][128] (k contiguous). 4x 128x128 + 1x 128x64.
__global__ __launch_bounds__(256) void wconv(const float* __restrict__ Ws0, const float* __restrict__ Lw0,
                                             const float* __restrict__ Ws1, const float* __restrict__ Lw1,
                                             const float* __restrict__ Wts,
                                             ushort_t* s0h, ushort_t* s0l, ushort_t* l0h, ushort_t* l0l,
                                             ushort_t* s1h, ushort_t* s1l, ushort_t* l1h, ushort_t* l1l,
                                             ushort_t* tsh, ushort_t* tsl) {
    int i = blockIdx.x * 256 + threadIdx.x;
    const float* W; ushort_t* oh; ushort_t* ol; int idx, k, n;
    if (i < 65536) {
        int m = i >> 14; idx = i & 16383;
        W = (m == 0) ? Ws0 : (m == 1) ? Lw0 : (m == 2) ? Ws1 : Lw1;
        oh = (m == 0) ? s0h : (m == 1) ? l0h : (m == 2) ? s1h : l1h;
        ol = (m == 0) ? s0l : (m == 1) ? l0l : (m == 2) ? s1l : l1l;
        k = idx >> 7; n = idx & 127;
    } else if (i < 73728) {
        idx = i - 65536; W = Wts; oh = tsh; ol = tsl;
        k = idx >> 6; n = idx & 63;
    } else return;
    float v = W[idx];
    ushort_t hi = f2bf(v);
    ushort_t lo = f2bf(v - bfu2f(hi));
    oh[n * 128 + k] = hi;
    ol[n * 128 + k] = lo;
}

// ---------------- MFMA GEMM: Y1 = X@W1 (bf16 out + fused es), optional Y2 = X@W2 (fp32),
//                  optional ed = X@wed.  K=128. Block = 4 waves, 64 rows; wave owns 16 rows.
//                  No LDS: A-frags from row-major X (fp32 or bf16 hi/lo pair), B-frags from WT[n][k].
template <int CN, bool DUAL, bool FP32IN>
__global__ __launch_bounds__(256) void gemm_mfma(const float* __restrict__ Xf,
                                                 const ushort_t* __restrict__ Xh, const ushort_t* __restrict__ Xl,
                                                 const ushort_t* __restrict__ W1h, const ushort_t* __restrict__ W1l,
                                                 const ushort_t* __restrict__ W2h, const ushort_t* __restrict__ W2l,
                                                 ushort_t* __restrict__ Y1, float* __restrict__ Y2,
                                                 const float* __restrict__ avec, float* __restrict__ evec,
                                                 const float* __restrict__ wed, float* __restrict__ edv,
                                                 int N) {
    constexpr int NI = CN / 16;
    const int tid = threadIdx.x;
    const int w = tid >> 6, l = tid & 63;
    const int col = l & 15, q = l >> 4;
    const int row0 = blockIdx.x * 64 + w * 16;
    const int arow = row0 + col;            // row this lane stages A for
    f32x4 acc1[NI];
    f32x4 acc2[DUAL ? NI : 1];
    #pragma unroll
    for (int ni = 0; ni < NI; ++ni) {
        #pragma unroll
        for (int r = 0; r < 4; ++r) acc1[ni][r] = 0.f;
    }
    if (DUAL) {
        #pragma unroll
        for (int ni = 0; ni < NI; ++ni) {
            #pragma unroll
            for (int r = 0; r < 4; ++r) acc2[ni][r] = 0.f;
        }
    }
    float ped = 0.f;

    #pragma unroll
    for (int kc = 0; kc < 4; ++kc) {
        const int kbase = kc * 32 + q * 8;
        short8 Ah, Al;
        if (FP32IN) {
            float xv[8];
            if (arow < N) {
                float4 a0 = *(const float4*)&Xf[(size_t)arow * 128 + kbase];
                float4 a1 = *(const float4*)&Xf[(size_t)arow * 128 + kbase + 4];
                xv[0] = a0.x; xv[1] = a0.y; xv[2] = a0.z; xv[3] = a0.w;
                xv[4] = a1.x; xv[5] = a1.y; xv[6] = a1.z; xv[7] = a1.w;
            } else {
                #pragma unroll
                for (int j = 0; j < 8; ++j) xv[j] = 0.f;
            }
            #pragma unroll
            for (int j = 0; j < 8; ++j) {
                ushort_t hi = f2bf(xv[j]);
                ushort_t lo = f2bf(xv[j] - bfu2f(hi));
                Ah[j] = (short)hi;
                Al[j] = (short)lo;
            }
            if (wed) {
                float4 w0 = *(const float4*)&wed[kbase];
                float4 w1 = *(const float4*)&wed[kbase + 4];
                ped += xv[0] * w0.x + xv[1] * w0.y + xv[2] * w0.z + xv[3] * w0.w
                     + xv[4] * w1.x + xv[5] * w1.y + xv[6] * w1.z + xv[7] * w1.w;
            }
        } else {
            if (arow < N) {
                Ah = *(const short8*)&Xh[(size_t)arow * 128 + kbase];
                Al = *(const short8*)&Xl[(size_t)arow * 128 + kbase];
            } else {
                #pragma unroll
                for (int j = 0; j < 8; ++j) { Ah[j] = 0; Al[j] = 0; }
            }
            if (wed) {
                float4 w0 = *(const float4*)&wed[kbase];
                float4 w1 = *(const float4*)&wed[kbase + 4];
                float wv[8] = {w0.x, w0.y, w0.z, w0.w, w1.x, w1.y, w1.z, w1.w};
                #pragma unroll
                for (int j = 0; j < 8; ++j) {
                    float x = bfu2f((ushort_t)Ah[j]) + bfu2f((ushort_t)Al[j]);
                    ped += x * wv[j];
                }
            }
        }
        #pragma unroll
        for (int ni = 0; ni < NI; ++ni) {
            const size_t boff = (size_t)(ni * 16 + col) * 128 + kbase;
            short8 B1h = *(const short8*)&W1h[boff];
            short8 B1l = *(const short8*)&W1l[boff];
            acc1[ni] = mfma16(Ah, B1h, acc1[ni]);
            acc1[ni] = mfma16(Al, B1h, acc1[ni]);
            acc1[ni] = mfma16(Ah, B1l, acc1[ni]);
            if (DUAL) {
                short8 B2h = *(const short8*)&W2h[boff];
                short8 B2l = *(const short8*)&W2l[boff];
                acc2[ni] = mfma16(Ah, B2h, acc2[ni]);
                acc2[ni] = mfma16(Al, B2h, acc2[ni]);
                acc2[ni] = mfma16(Ah, B2l, acc2[ni]);
            }
        }
    }

    // stores: C/D layout row=(q*4+r), col=l&15 within each 16x16 tile
    #pragma unroll
    for (int ni = 0; ni < NI; ++ni) {
        #pragma unroll
        for (int r = 0; r < 4; ++r) {
            int mrow = row0 + q * 4 + r;
            if (mrow < N) {
                Y1[(size_t)mrow * CN + ni * 16 + col] = f2bf(acc1[ni][r]);
                if (DUAL) Y2[(size_t)mrow * CN + ni * 16 + col] = acc2[ni][r];
            }
        }
    }
    // fused es = Y1 . avec
    float av[NI];
    #pragma unroll
    for (int ni = 0; ni < NI; ++ni) av[ni] = avec[ni * 16 + col];
    #pragma unroll
    for (int r = 0; r < 4; ++r) {
        float p = 0.f;
        #pragma unroll
        for (int ni = 0; ni < NI; ++ni) p += acc1[ni][r] * av[ni];
        p += __shfl_xor(p, 1, 64);
        p += __shfl_xor(p, 2, 64);
        p += __shfl_xor(p, 4, 64);
        p += __shfl_xor(p, 8, 64);
        int mrow = row0 + q * 4 + r;
        if (col == 0 && mrow < N) evec[mrow] = p;
    }
    // fused ed = X . wed (A-side: lane's partial covers m=col, its 8 k's; reduce over q)
    if (wed) {
        ped += __shfl_xor(ped, 16, 64);
        ped += __shfl_xor(ped, 32, 64);
        if (q == 0 && arow < N) edv[arow] = ped;
    }
}

// ---------------- matvec (x_fp @ wedt), one wave per row ----------------
template <int K>
__global__ __launch_bounds__(256) void matvec_k(const float* __restrict__ X, const float* __restrict__ v,
                                                float* __restrict__ y, int N) {
    int lane = threadIdx.x & 63, wid = threadIdx.x >> 6;
    int node = blockIdx.x * 4 + wid;
    if (node >= N) return;
    float s = X[node * K + lane] * v[lane];
    if (K > 64) s += X[node * K + 64 + lane] * v[64 + lane];
    #pragma unroll
    for (int off = 32; off; off >>= 1) s += __shfl_down(s, off, 64);
    if (lane == 0) y[node] = s;
}

// ---------------- GAT aggregate (pano, C=128, bf16 hs gather) -> h as bf16 hi/lo ----------------
__global__ __launch_bounds__(256) void agg_pano4(const int* __restrict__ ptr, const int* __restrict__ col,
                                                 const float* __restrict__ es, const float* __restrict__ ed,
                                                 const ushort_t* __restrict__ hsb, const float* __restrict__ lin,
                                                 const float* __restrict__ b, const float* __restrict__ Lb,
                                                 uint_t* __restrict__ hh, uint_t* __restrict__ hl, int N) {
    int lane = threadIdx.x & 63, wid = threadIdx.x >> 6;
    int node = blockIdx.x * 4 + wid;
    if (node >= N) return;
    int beg = ptr[node], end = ptr[node + 1];
    float edn = ed[node];
    int ch = lane * 2;
    float ax = 0.f, ay = 0.f, den = 0.f;
    int i = beg;
    for (; i + 8 <= end; i += 8) {
        int s[8];
        #pragma unroll
        for (int u = 0; u < 8; ++u) s[u] = col[i + u];
        float w[8];
        #pragma unroll
        for (int u = 0; u < 8; ++u) {
            float e = es[s[u]] + edn;
            e = fmaxf(e, 0.2f * e);
            w[u] = __expf(e);
        }
        uint_t hv[8];
        #pragma unroll
        for (int u = 0; u < 8; ++u) hv[u] = *(const uint_t*)&hsb[(size_t)s[u] * 128 + ch];
        #pragma unroll
        for (int u = 0; u < 8; ++u) {
            float hx = __uint_as_float((hv[u] & 0xffffu) << 16);
            float hy = __uint_as_float(hv[u] & 0xffff0000u);
            den += w[u];
            ax += w[u] * hx;
            ay += w[u] * hy;
        }
    }
    for (; i < end; ++i) {
        int s = col[i];
        float e = es[s] + edn;
        e = fmaxf(e, 0.2f * e);
        float wgt = __expf(e);
        uint_t hv = *(const uint_t*)&hsb[(size_t)s * 128 + ch];
        float hx = __uint_as_float((hv & 0xffffu) << 16);
        float hy = __uint_as_float(hv & 0xffff0000u);
        den += wgt;
        ax += wgt * hx;
        ay += wgt * hy;
    }
    float inv = (end > beg) ? (1.f / den) : 0.f;
    float2 l2 = *(const float2*)&lin[(size_t)node * 128 + ch];
    float2 bb = *(const float2*)&b[ch];
    float2 lb = *(const float2*)&Lb[ch];
    float ox = fmaxf(ax * inv + bb.x + l2.x + lb.x, 0.f);
    float oy = fmaxf(ay * inv + bb.y + l2.y + lb.y, 0.f);
    ushort_t hx = f2bf(ox), hy = f2bf(oy);
    hh[(size_t)node * 64 + lane] = (uint_t)hx | ((uint_t)hy << 16);
    hl[(size_t)node * 64 + lane] = pack2bf(ox - bfu2f(hx), oy - bfu2f(hy));
}

// ---------------- translate aggregate (C=64, bf16 hs gather) ----------------
__global__ __launch_bounds__(256) void agg_fp3(const int* __restrict__ ptr, const int* __restrict__ col,
                                               const float* __restrict__ es, const float* __restrict__ ed,
                                               const ushort_t* __restrict__ hsb, const float* __restrict__ bt,
                                               float* __restrict__ out, int N) {
    int lane = threadIdx.x & 63, wid = threadIdx.x >> 6;
    int node = blockIdx.x * 4 + wid;
    if (node >= N) return;
    int beg = ptr[node], end = ptr[node + 1];
    float edn = ed[node];
    float acc = 0.f, den = 0.f;
    int i = beg;
    for (; i + 8 <= end; i += 8) {
        int s[8];
        #pragma unroll
        for (int u = 0; u < 8; ++u) s[u] = col[i + u];
        float w[8];
        #pragma unroll
        for (int u = 0; u < 8; ++u) {
            float e = es[s[u]] + edn;
            e = fmaxf(e, 0.2f * e);
            w[u] = __expf(e);
        }
        ushort_t hv[8];
        #pragma unroll
        for (int u = 0; u < 8; ++u) hv[u] = hsb[(size_t)s[u] * 64 + lane];
        #pragma unroll
        for (int u = 0; u < 8; ++u) {
            den += w[u];
            acc += w[u] * bfu2f(hv[u]);
        }
    }
    for (; i < end; ++i) {
        int s = col[i];
        float e = es[s] + edn;
        e = fmaxf(e, 0.2f * e);
        float wgt = __expf(e);
        den += wgt;
        acc += wgt * bfu2f(hsb[(size_t)s * 64 + lane]);
    }
    float inv = (end > beg) ? (1.f / den) : 0.f;
    out[(size_t)node * 64 + lane] = acc * inv + bt[lane];
}

extern "C" void kernel_launch(void* const* d_in, const int* in_sizes, int n_in,
                              void* d_out, int out_size, void* d_ws, size_t ws_size,
                              hipStream_t stream) {
    const float* x_pano = (const float*)d_in[0];
    const float* x_fp   = (const float*)d_in[1];
    const float* Ws0 = (const float*)d_in[2];
    const float* Wd0 = (const float*)d_in[3];
    const float* as0 = (const float*)d_in[4];
    const float* ad0 = (const float*)d_in[5];
    const float* b0  = (const float*)d_in[6];
    const float* Lw0 = (const float*)d_in[7];
    const float* Lb0 = (const float*)d_in[8];
    const float* Ws1 = (const float*)d_in[9];
    const float* Wd1 = (const float*)d_in[10];
    const float* as1 = (const float*)d_in[11];
    const float* ad1 = (const float*)d_in[12];
    const float* b1  = (const float*)d_in[13];
    const float* Lw1 = (const float*)d_in[14];
    const float* Lb1 = (const float*)d_in[15];
    const float* Wts = (const float*)d_in[16];
    const float* Wtd = (const float*)d_in[17];
    const float* ats = (const float*)d_in[18];
    const float* atd = (const float*)d_in[19];
    const float* bt  = (const float*)d_in[20];
    const int* edge_pp = (const int*)d_in[21];
    const int* pf_src  = (const int*)d_in[22];
    const int* pf_dst  = (const int*)d_in[23];
    float* out = (float*)d_out;

    char* wsp = (char*)d_ws;
    size_t off = 0;
    auto alloc = [&](size_t bytes) -> char* {
        char* p = wsp + off;
        off += (bytes + 255) & ~(size_t)255;
        return p;
    };
    ushort_t* hsb  = (ushort_t*)alloc(sizeof(ushort_t) * N_PANO * HID);   // 12.8 MB
    float* lin     = (float*)alloc(sizeof(float) * N_PANO * HID);         // 25.6 MB
    uint_t* hh     = (uint_t*)alloc(sizeof(uint_t) * N_PANO * 64);        // 12.8 MB
    uint_t* hl     = (uint_t*)alloc(sizeof(uint_t) * N_PANO * 64);        // 12.8 MB
    ushort_t* hstb = (ushort_t*)alloc(sizeof(ushort_t) * N_PANO * OUT_C); // 6.4 MB
    float* es   = (float*)alloc(sizeof(float) * N_PANO);
    float* ed   = (float*)alloc(sizeof(float) * N_PANO);
    float* edt  = (float*)alloc(sizeof(float) * N_FP);
    float* wed0 = (float*)alloc(sizeof(float) * HID);
    float* wed1 = (float*)alloc(sizeof(float) * HID);
    float* wedt = (float*)alloc(sizeof(float) * OUT_C);
    // weight hi/lo transposed buffers ([n][128])
    ushort_t* s0h = (ushort_t*)alloc(sizeof(ushort_t) * 128 * 128);
    ushort_t* s0l = (ushort_t*)alloc(sizeof(ushort_t) * 128 * 128);
    ushort_t* l0h = (ushort_t*)alloc(sizeof(ushort_t) * 128 * 128);
    ushort_t* l0l = (ushort_t*)alloc(sizeof(ushort_t) * 128 * 128);
    ushort_t* s1h = (ushort_t*)alloc(sizeof(ushort_t) * 128 * 128);
    ushort_t* s1l = (ushort_t*)alloc(sizeof(ushort_t) * 128 * 128);
    ushort_t* l1h = (ushort_t*)alloc(sizeof(ushort_t) * 128 * 128);
    ushort_t* l1l = (ushort_t*)alloc(sizeof(ushort_t) * 128 * 128);
    ushort_t* tsh = (ushort_t*)alloc(sizeof(ushort_t) * 64 * 128);
    ushort_t* tsl = (ushort_t*)alloc(sizeof(ushort_t) * 64 * 128);
    int* cnt    = (int*)alloc(sizeof(int) * N_PANO);
    int* cur    = (int*)alloc(sizeof(int) * N_PANO);
    int* bsum   = (int*)alloc(sizeof(int) * 64);
    int* ptr_pp = (int*)alloc(sizeof(int) * (N_PANO + 1));
    int* col_pp = (int*)alloc(sizeof(int) * E_PP);
    int* ptr_pf = (int*)alloc(sizeof(int) * (N_FP + 1));
    int* col_pf = (int*)alloc(sizeof(int) * E_PF);

    const int* pp_src = edge_pp;
    const int* pp_dst = edge_pp + E_PP;

    // ---- CSR build (pp) ----
    {
        int nb = cdiv(N_PANO, 1024);
        zero_i32<<<cdiv(N_PANO, 256), 256, 0, stream>>>(cnt, N_PANO);
        count_k<<<cdiv(E_PP, 256), 256, 0, stream>>>(pp_dst, E_PP, cnt);
        scan_local<<<nb, 1024, 0, stream>>>(cnt, ptr_pp, bsum, N_PANO);
        scan_bsum<<<1, 64, 0, stream>>>(bsum, nb, &ptr_pp[N_PANO]);
        scan_add<<<nb, 1024, 0, stream>>>(ptr_pp, cur, bsum, N_PANO);
        scatter_k<<<cdiv(E_PP, 256), 256, 0, stream>>>(pp_src, pp_dst, E_PP, cur, col_pp);
    }
    // ---- CSR build (pf) ----
    {
        int nb = cdiv(N_FP, 1024);
        zero_i32<<<cdiv(N_FP, 256), 256, 0, stream>>>(cnt, N_FP);
        count_k<<<cdiv(E_PF, 256), 256, 0, stream>>>(pf_dst, E_PF, cnt);
        scan_local<<<nb, 1024, 0, stream>>>(cnt, ptr_pf, bsum, N_FP);
        scan_bsum<<<1, 64, 0, stream>>>(bsum, nb, &ptr_pf[N_FP]);
        scan_add<<<nb, 1024, 0, stream>>>(ptr_pf, cur, bsum, N_FP);
        scatter_k<<<cdiv(E_PF, 256), 256, 0, stream>>>(pf_src, pf_dst, E_PF, cur, col_pf);
    }
    // ---- fold Wd @ a_d ; convert/transpose weights ----
    wed_wave<<<HID, 64, 0, stream>>>(Wd0, ad0, wed0, HID);
    wed_wave<<<HID, 64, 0, stream>>>(Wd1, ad1, wed1, HID);
    wed_wave<<<OUT_C, 64, 0, stream>>>(Wtd, atd, wedt, OUT_C);
    wconv<<<288, 256, 0, stream>>>(Ws0, Lw0, Ws1, Lw1, Wts,
                                   s0h, s0l, l0h, l0l, s1h, s1l, l1h, l1l, tsh, tsl);

    const int gemm_grid = cdiv(N_PANO, 64);

    // ---- layer 0 (fp32 input) ----
    gemm_mfma<128, true, true><<<gemm_grid, 256, 0, stream>>>(
        x_pano, nullptr, nullptr, s0h, s0l, l0h, l0l,
        hsb, lin, as0, es, wed0, ed, N_PANO);
    agg_pano4<<<cdiv(N_PANO, 4), 256, 0, stream>>>(ptr_pp, col_pp, es, ed, hsb, lin, b0, Lb0, hh, hl, N_PANO);

    // ---- layer 1 (bf16 hi/lo input) ----
    gemm_mfma<128, true, false><<<gemm_grid, 256, 0, stream>>>(
        nullptr, (const ushort_t*)hh, (const ushort_t*)hl, s1h, s1l, l1h, l1l,
        hsb, lin, as1, es, wed1, ed, N_PANO);
    agg_pano4<<<cdiv(N_PANO, 4), 256, 0, stream>>>(ptr_pp, col_pp, es, ed, hsb, lin, b1, Lb1, hh, hl, N_PANO);

    // ---- translate (pano -> footprint) ----
    gemm_mfma<64, false, false><<<gemm_grid, 256, 0, stream>>>(
        nullptr, (const ushort_t*)hh, (const ushort_t*)hl, tsh, tsl, nullptr, nullptr,
        hstb, nullptr, ats, es, nullptr, nullptr, N_PANO);
    matvec_k<64><<<cdiv(N_FP, 4), 256, 0, stream>>>(x_fp, wedt, edt, N_FP);
    agg_fp3<<<cdiv(N_FP, 4), 256, 0, stream>>>(ptr_pf, col_pf, es, edt, hstb, bt, out, N_FP);
}

// Round 5
// 399.483 us; speedup vs baseline: 1.2402x; 1.2402x over previous
//
#include <hip/hip_runtime.h>
#include <hip/hip_bf16.h>
#include <math.h>

#define N_PANO 50000
#define N_FP   10000
#define HID    128
#define OUT_C  64
#define E_PP   800000
#define E_PF   50000

typedef unsigned short ushort_t;
typedef unsigned int uint_t;
typedef __attribute__((ext_vector_type(8))) short short8;
typedef __attribute__((ext_vector_type(4))) float f32x4;

static inline int cdiv(int a, int b) { return (a + b - 1) / b; }

__device__ inline ushort_t f2bf(float x) {
    __hip_bfloat16 h = __float2bfloat16(x);   // RNE
    return *reinterpret_cast<ushort_t*>(&h);
}
__device__ inline float bfu2f(ushort_t u) {
    return __uint_as_float(((uint_t)u) << 16);
}
__device__ inline uint_t pack2bf(float a, float b) {
    return (uint_t)f2bf(a) | ((uint_t)f2bf(b) << 16);
}
__device__ inline f32x4 mfma16(short8 a, short8 b, f32x4 c) {
    return __builtin_amdgcn_mfma_f32_16x16x32_bf16(a, b, c, 0, 0, 0);
}

// ---------------- CSR build ----------------
__global__ __launch_bounds__(256) void zero_i32(int* p, int n) {
    int i = blockIdx.x * 256 + threadIdx.x;
    if (i < n) p[i] = 0;
}

__global__ __launch_bounds__(256) void count_k(const int* __restrict__ dst, int E, int* __restrict__ cnt) {
    int i = blockIdx.x * 256 + threadIdx.x;
    if (i < E) atomicAdd(&cnt[dst[i]], 1);
}

__global__ __launch_bounds__(1024) void scan_local(const int* __restrict__ cnt, int* __restrict__ ptr,
                                                   int* __restrict__ bsum, int n) {
    __shared__ int wsum[16];
    int tid = threadIdx.x, lane = tid & 63, wid = tid >> 6;
    int i = blockIdx.x * 1024 + tid;
    int v = (i < n) ? cnt[i] : 0;
    int incl = v;
    #pragma unroll
    for (int off = 1; off < 64; off <<= 1) {
        int t = __shfl_up(incl, off, 64);
        if (lane >= off) incl += t;
    }
    if (lane == 63) wsum[wid] = incl;
    __syncthreads();
    if (tid == 0) {
        int run = 0;
        #pragma unroll
        for (int w = 0; w < 16; ++w) { int t = wsum[w]; wsum[w] = run; run += t; }
        bsum[blockIdx.x] = run;
    }
    __syncthreads();
    int excl = wsum[wid] + incl - v;
    if (i < n) ptr[i] = excl;
}

__global__ __launch_bounds__(64) void scan_bsum(int* __restrict__ bsum, int nb, int* __restrict__ total_out) {
    int lane = threadIdx.x;
    int v = (lane < nb) ? bsum[lane] : 0;
    int incl = v;
    #pragma unroll
    for (int off = 1; off < 64; off <<= 1) {
        int t = __shfl_up(incl, off, 64);
        if (lane >= off) incl += t;
    }
    if (lane < nb) bsum[lane] = incl - v;
    if (lane == 63) *total_out = incl;
}

__global__ __launch_bounds__(1024) void scan_add(int* __restrict__ ptr, int* __restrict__ cur,
                                                 const int* __restrict__ bsum, int n) {
    int i = blockIdx.x * 1024 + threadIdx.x;
    if (i < n) {
        int v = ptr[i] + bsum[blockIdx.x];
        ptr[i] = v;
        cur[i] = v;
    }
}

__global__ __launch_bounds__(256) void scatter_k(const int* __restrict__ src, const int* __restrict__ dst,
                                                 int E, int* __restrict__ cur, int* __restrict__ col) {
    int i = blockIdx.x * 256 + threadIdx.x;
    if (i < E) {
        int p = atomicAdd(&cur[dst[i]], 1);
        col[p] = src[i];
    }
}

// ---------------- wed[i] = sum_j W[i][j]*a[j] ----------------
__global__ __launch_bounds__(64) void wed_wave(const float* __restrict__ W, const float* __restrict__ a,
                                               float* __restrict__ o, int C) {
    int r = blockIdx.x, lane = threadIdx.x;
    float s = 0.f;
    for (int j = lane; j < C; j += 64) s += W[r * C + j] * a[j];
    #pragma unroll
    for (int off = 32; off; off >>= 1) s += __shfl_down(s, off, 64);
    if (lane == 0) o[r] = s;
}

// ---------------- weight -> bf16 hi/lo split, permuted to MFMA B-fragment order ----
// Dest element layout (bf16): d = (((kc>>1)*NI*2) + ni*2 + (kc&1))*512 + l*8 + j
//   source: W[k][C] with n = ni*16 + (l&15), k = kc*32 + (l>>4)*8 + j
// so a K-phase (kc pair) is a contiguous 16*NI/8 KB slab and the LDS stage is a
// linear uint4 copy; in-kernel fragment reads are lane-contiguous ds_read_b128.
__global__ __launch_bounds__(256) void wconv(const float* __restrict__ Ws0, const float* __restrict__ Lw0,
                                             const float* __restrict__ Ws1, const float* __restrict__ Lw1,
                                             const float* __restrict__ Wts,
                                             ushort_t* s0h, ushort_t* s0l, ushort_t* l0h, ushort_t* l0l,
                                             ushort_t* s1h, ushort_t* s1l, ushort_t* l1h, ushort_t* l1l,
                                             ushort_t* tsh, ushort_t* tsl) {
    int i = blockIdx.x * 256 + threadIdx.x;
    const float* W; ushort_t* oh; ushort_t* ol;
    int d, NIc, Cc;
    if (i < 65536) {
        int m = i >> 14; d = i & 16383;
        W = (m == 0) ? Ws0 : (m == 1) ? Lw0 : (m == 2) ? Ws1 : Lw1;
        oh = (m == 0) ? s0h : (m == 1) ? l0h : (m == 2) ? s1h : l1h;
        ol = (m == 0) ? s0l : (m == 1) ? l0l : (m == 2) ? s1l : l1l;
        NIc = 8; Cc = 128;
    } else if (i < 73728) {
        d = i - 65536; W = Wts; oh = tsh; ol = tsl;
        NIc = 4; Cc = 64;
    } else return;
    int j = d & 7, l = (d >> 3) & 63;
    int kcl = (d >> 9) & 1;
    int ni = (d >> 10) & (NIc - 1);
    int p = d >> (10 + (NIc == 8 ? 3 : 2));
    int kc = p * 2 + kcl;
    int n = ni * 16 + (l & 15);
    int k = kc * 32 + (l >> 4) * 8 + j;
    float v = W[k * Cc + n];
    ushort_t hi = f2bf(v);
    ushort_t lo = f2bf(v - bfu2f(hi));
    oh[d] = hi;
    ol[d] = lo;
}

// ---------------- MFMA GEMM with LDS-staged fragment-order weights ----------------
// Block: 256 thr (4 waves) x 128 rows; wave owns 32 rows (2 m-subtiles of 16).
// K=128 in 2 phases of 64; per phase stage NMAT matrices' fragment slabs into LDS.
// Y1 = X@W1 -> bf16 (+fused es = Y1.avec); DUAL: Y2 = X@W2 -> fp32; opt ed = X.wed.
template <int CN, bool DUAL, bool FP32IN>
__global__ __launch_bounds__(256, 2) void gemm_mfma(const float* __restrict__ Xf,
                                                 const ushort_t* __restrict__ Xh, const ushort_t* __restrict__ Xl,
                                                 const ushort_t* __restrict__ W1h, const ushort_t* __restrict__ W1l,
                                                 const ushort_t* __restrict__ W2h, const ushort_t* __restrict__ W2l,
                                                 ushort_t* __restrict__ Y1, float* __restrict__ Y2,
                                                 const float* __restrict__ avec, float* __restrict__ evec,
                                                 const float* __restrict__ wed, float* __restrict__ edv,
                                                 int N) {
    constexpr int NI = CN / 16;
    constexpr int NMAT = DUAL ? 4 : 2;
    constexpr int SLAB = NI * 1024;          // ushorts per matrix per phase
    __shared__ ushort_t Bsh[NMAT * SLAB];    // 64 KB dual / 16 KB single
    const int tid = threadIdx.x;
    const int w = tid >> 6, l = tid & 63;
    const int col = l & 15, q = l >> 4;
    const int row0 = blockIdx.x * 128 + w * 32;
    f32x4 acc1[2][NI];
    f32x4 acc2[2][DUAL ? NI : 1];
    #pragma unroll
    for (int m = 0; m < 2; ++m)
        #pragma unroll
        for (int ni = 0; ni < NI; ++ni)
            #pragma unroll
            for (int r = 0; r < 4; ++r) acc1[m][ni][r] = 0.f;
    if (DUAL) {
        #pragma unroll
        for (int m = 0; m < 2; ++m)
            #pragma unroll
            for (int ni = 0; ni < NI; ++ni)
                #pragma unroll
                for (int r = 0; r < 4; ++r) acc2[m][ni][r] = 0.f;
    }
    float ped[2] = {0.f, 0.f};

    const ushort_t* Wp[NMAT];
    Wp[0] = W1h; Wp[1] = W1l;
    if (DUAL) { Wp[2] = W2h; Wp[3] = W2l; }

    #pragma unroll
    for (int p = 0; p < 2; ++p) {
        if (p) __syncthreads();   // protect LDS before restage
        // stage phase p: linear uint4 copy, coalesced, conflict-free
        #pragma unroll
        for (int m = 0; m < NMAT; ++m) {
            const uint4* src = (const uint4*)Wp[m] + p * (SLAB / 8);
            uint4* dst = (uint4*)&Bsh[m * SLAB];
            #pragma unroll
            for (int f = tid; f < SLAB / 8; f += 256) dst[f] = src[f];
        }
        __syncthreads();
        #pragma unroll
        for (int kcl = 0; kcl < 2; ++kcl) {
            const int kc = p * 2 + kcl;
            const int k0 = kc * 32 + q * 8;
            short8 Ah[2], Al[2];
            #pragma unroll
            for (int m = 0; m < 2; ++m) {
                const int arow = row0 + m * 16 + col;
                if (FP32IN) {
                    float xv[8];
                    if (arow < N) {
                        float4 a0 = *(const float4*)&Xf[(size_t)arow * 128 + k0];
                        float4 a1 = *(const float4*)&Xf[(size_t)arow * 128 + k0 + 4];
                        xv[0] = a0.x; xv[1] = a0.y; xv[2] = a0.z; xv[3] = a0.w;
                        xv[4] = a1.x; xv[5] = a1.y; xv[6] = a1.z; xv[7] = a1.w;
                    } else {
                        #pragma unroll
                        for (int j = 0; j < 8; ++j) xv[j] = 0.f;
                    }
                    #pragma unroll
                    for (int j = 0; j < 8; ++j) {
                        ushort_t hi = f2bf(xv[j]);
                        ushort_t lo = f2bf(xv[j] - bfu2f(hi));
                        Ah[m][j] = (short)hi;
                        Al[m][j] = (short)lo;
                    }
                    if (wed) {
                        float4 w0 = *(const float4*)&wed[k0];
                        float4 w1 = *(const float4*)&wed[k0 + 4];
                        ped[m] += xv[0] * w0.x + xv[1] * w0.y + xv[2] * w0.z + xv[3] * w0.w
                                + xv[4] * w1.x + xv[5] * w1.y + xv[6] * w1.z + xv[7] * w1.w;
                    }
                } else {
                    if (arow < N) {
                        Ah[m] = *(const short8*)&Xh[(size_t)arow * 128 + k0];
                        Al[m] = *(const short8*)&Xl[(size_t)arow * 128 + k0];
                    } else {
                        #pragma unroll
                        for (int j = 0; j < 8; ++j) { Ah[m][j] = 0; Al[m][j] = 0; }
                    }
                    if (wed) {
                        float4 w0 = *(const float4*)&wed[k0];
                        float4 w1 = *(const float4*)&wed[k0 + 4];
                        float wv[8] = {w0.x, w0.y, w0.z, w0.w, w1.x, w1.y, w1.z, w1.w};
                        #pragma unroll
                        for (int j = 0; j < 8; ++j)
                            ped[m] += (bfu2f((ushort_t)Ah[m][j]) + bfu2f((ushort_t)Al[m][j])) * wv[j];
                    }
                }
            }
            #pragma unroll
            for (int ni = 0; ni < NI; ++ni) {
                const int lb = ((ni * 2 + kcl) * 64 + l) * 8;
                short8 B1h = *(const short8*)&Bsh[0 * SLAB + lb];
                short8 B1l = *(const short8*)&Bsh[1 * SLAB + lb];
                #pragma unroll
                for (int m = 0; m < 2; ++m) {
                    acc1[m][ni] = mfma16(Ah[m], B1h, acc1[m][ni]);
                    acc1[m][ni] = mfma16(Al[m], B1h, acc1[m][ni]);
                    acc1[m][ni] = mfma16(Ah[m], B1l, acc1[m][ni]);
                }
                if (DUAL) {
                    short8 B2h = *(const short8*)&Bsh[2 * SLAB + lb];
                    short8 B2l = *(const short8*)&Bsh[3 * SLAB + lb];
                    #pragma unroll
                    for (int m = 0; m < 2; ++m) {
                        acc2[m][ni] = mfma16(Ah[m], B2h, acc2[m][ni]);
                        acc2[m][ni] = mfma16(Al[m], B2h, acc2[m][ni]);
                        acc2[m][ni] = mfma16(Ah[m], B2l, acc2[m][ni]);
                    }
                }
            }
        }
    }

    // stores: C/D layout row=(q*4+r), col=l&15 per 16x16 tile
    #pragma unroll
    for (int m = 0; m < 2; ++m) {
        #pragma unroll
        for (int ni = 0; ni < NI; ++ni) {
            #pragma unroll
            for (int r = 0; r < 4; ++r) {
                int mrow = row0 + m * 16 + q * 4 + r;
                if (mrow < N) {
                    Y1[(size_t)mrow * CN + ni * 16 + col] = f2bf(acc1[m][ni][r]);
                    if (DUAL) Y2[(size_t)mrow * CN + ni * 16 + col] = acc2[m][ni][r];
                }
            }
        }
    }
    // fused es = Y1 . avec
    float av[NI];
    #pragma unroll
    for (int ni = 0; ni < NI; ++ni) av[ni] = avec[ni * 16 + col];
    #pragma unroll
    for (int m = 0; m < 2; ++m) {
        #pragma unroll
        for (int r = 0; r < 4; ++r) {
            float pp = 0.f;
            #pragma unroll
            for (int ni = 0; ni < NI; ++ni) pp += acc1[m][ni][r] * av[ni];
            pp += __shfl_xor(pp, 1, 64);
            pp += __shfl_xor(pp, 2, 64);
            pp += __shfl_xor(pp, 4, 64);
            pp += __shfl_xor(pp, 8, 64);
            int mrow = row0 + m * 16 + q * 4 + r;
            if (col == 0 && mrow < N) evec[mrow] = pp;
        }
    }
    // fused ed = X . wed (A-side; reduce over q)
    if (wed) {
        #pragma unroll
        for (int m = 0; m < 2; ++m) {
            ped[m] += __shfl_xor(ped[m], 16, 64);
            ped[m] += __shfl_xor(ped[m], 32, 64);
            int arow = row0 + m * 16 + col;
            if (q == 0 && arow < N) edv[arow] = ped[m];
        }
    }
}

// ---------------- matvec (x_fp @ wedt), one wave per row ----------------
template <int K>
__global__ __launch_bounds__(256) void matvec_k(const float* __restrict__ X, const float* __restrict__ v,
                                                float* __restrict__ y, int N) {
    int lane = threadIdx.x & 63, wid = threadIdx.x >> 6;
    int node = blockIdx.x * 4 + wid;
    if (node >= N) return;
    float s = X[node * K + lane] * v[lane];
    if (K > 64) s += X[node * K + 64 + lane] * v[64 + lane];
    #pragma unroll
    for (int off = 32; off; off >>= 1) s += __shfl_down(s, off, 64);
    if (lane == 0) y[node] = s;
}

// ---------------- GAT aggregate (pano, C=128, bf16 hs gather) -> h as bf16 hi/lo ----------------
__global__ __launch_bounds__(256) void agg_pano4(const int* __restrict__ ptr, const int* __restrict__ col,
                                                 const float* __restrict__ es, const float* __restrict__ ed,
                                                 const ushort_t* __restrict__ hsb, const float* __restrict__ lin,
                                                 const float* __restrict__ b, const float* __restrict__ Lb,
                                                 uint_t* __restrict__ hh, uint_t* __restrict__ hl, int N) {
    int lane = threadIdx.x & 63, wid = threadIdx.x >> 6;
    int node = blockIdx.x * 4 + wid;
    if (node >= N) return;
    int beg = ptr[node], end = ptr[node + 1];
    float edn = ed[node];
    int ch = lane * 2;
    float ax = 0.f, ay = 0.f, den = 0.f;
    int i = beg;
    for (; i + 8 <= end; i += 8) {
        int s[8];
        #pragma unroll
        for (int u = 0; u < 8; ++u) s[u] = col[i + u];
        float w[8];
        #pragma unroll
        for (int u = 0; u < 8; ++u) {
            float e = es[s[u]] + edn;
            e = fmaxf(e, 0.2f * e);
            w[u] = __expf(e);
        }
        uint_t hv[8];
        #pragma unroll
        for (int u = 0; u < 8; ++u) hv[u] = *(const uint_t*)&hsb[(size_t)s[u] * 128 + ch];
        #pragma unroll
        for (int u = 0; u < 8; ++u) {
            float hx = __uint_as_float((hv[u] & 0xffffu) << 16);
            float hy = __uint_as_float(hv[u] & 0xffff0000u);
            den += w[u];
            ax += w[u] * hx;
            ay += w[u] * hy;
        }
    }
    for (; i < end; ++i) {
        int s = col[i];
        float e = es[s] + edn;
        e = fmaxf(e, 0.2f * e);
        float wgt = __expf(e);
        uint_t hv = *(const uint_t*)&hsb[(size_t)s * 128 + ch];
        float hx = __uint_as_float((hv & 0xffffu) << 16);
        float hy = __uint_as_float(hv & 0xffff0000u);
        den += wgt;
        ax += wgt * hx;
        ay += wgt * hy;
    }
    float inv = (end > beg) ? (1.f / den) : 0.f;
    float2 l2 = *(const float2*)&lin[(size_t)node * 128 + ch];
    float2 bb = *(const float2*)&b[ch];
    float2 lb = *(const float2*)&Lb[ch];
    float ox = fmaxf(ax * inv + bb.x + l2.x + lb.x, 0.f);
    float oy = fmaxf(ay * inv + bb.y + l2.y + lb.y, 0.f);
    ushort_t hx = f2bf(ox), hy = f2bf(oy);
    hh[(size_t)node * 64 + lane] = (uint_t)hx | ((uint_t)hy << 16);
    hl[(size_t)node * 64 + lane] = pack2bf(ox - bfu2f(hx), oy - bfu2f(hy));
}

// ---------------- translate aggregate (C=64, bf16 hs gather) ----------------
__global__ __launch_bounds__(256) void agg_fp3(const int* __restrict__ ptr, const int* __restrict__ col,
                                               const float* __restrict__ es, const float* __restrict__ ed,
                                               const ushort_t* __restrict__ hsb, const float* __restrict__ bt,
                                               float* __restrict__ out, int N) {
    int lane = threadIdx.x & 63, wid = threadIdx.x >> 6;
    int node = blockIdx.x * 4 + wid;
    if (node >= N) return;
    int beg = ptr[node], end = ptr[node + 1];
    float edn = ed[node];
    float acc = 0.f, den = 0.f;
    int i = beg;
    for (; i + 8 <= end; i += 8) {
        int s[8];
        #pragma unroll
        for (int u = 0; u < 8; ++u) s[u] = col[i + u];
        float w[8];
        #pragma unroll
        for (int u = 0; u < 8; ++u) {
            float e = es[s[u]] + edn;
            e = fmaxf(e, 0.2f * e);
            w[u] = __expf(e);
        }
        ushort_t hv[8];
        #pragma unroll
        for (int u = 0; u < 8; ++u) hv[u] = hsb[(size_t)s[u] * 64 + lane];
        #pragma unroll
        for (int u = 0; u < 8; ++u) {
            den += w[u];
            acc += w[u] * bfu2f(hv[u]);
        }
    }
    for (; i < end; ++i) {
        int s = col[i];
        float e = es[s] + edn;
        e = fmaxf(e, 0.2f * e);
        float wgt = __expf(e);
        den += wgt;
        acc += wgt * bfu2f(hsb[(size_t)s * 64 + lane]);
    }
    float inv = (end > beg) ? (1.f / den) : 0.f;
    out[(size_t)node * 64 + lane] = acc * inv + bt[lane];
}

extern "C" void kernel_launch(void* const* d_in, const int* in_sizes, int n_in,
                              void* d_out, int out_size, void* d_ws, size_t ws_size,
                              hipStream_t stream) {
    const float* x_pano = (const float*)d_in[0];
    const float* x_fp   = (const float*)d_in[1];
    const float* Ws0 = (const float*)d_in[2];
    const float* Wd0 = (const float*)d_in[3];
    const float* as0 = (const float*)d_in[4];
    const float* ad0 = (const float*)d_in[5];
    const float* b0  = (const float*)d_in[6];
    const float* Lw0 = (const float*)d_in[7];
    const float* Lb0 = (const float*)d_in[8];
    const float* Ws1 = (const float*)d_in[9];
    const float* Wd1 = (const float*)d_in[10];
    const float* as1 = (const float*)d_in[11];
    const float* ad1 = (const float*)d_in[12];
    const float* b1  = (const float*)d_in[13];
    const float* Lw1 = (const float*)d_in[14];
    const float* Lb1 = (const float*)d_in[15];
    const float* Wts = (const float*)d_in[16];
    const float* Wtd = (const float*)d_in[17];
    const float* ats = (const float*)d_in[18];
    const float* atd = (const float*)d_in[19];
    const float* bt  = (const float*)d_in[20];
    const int* edge_pp = (const int*)d_in[21];
    const int* pf_src  = (const int*)d_in[22];
    const int* pf_dst  = (const int*)d_in[23];
    float* out = (float*)d_out;

    char* wsp = (char*)d_ws;
    size_t off = 0;
    auto alloc = [&](size_t bytes) -> char* {
        char* p = wsp + off;
        off += (bytes + 255) & ~(size_t)255;
        return p;
    };
    ushort_t* hsb  = (ushort_t*)alloc(sizeof(ushort_t) * N_PANO * HID);   // 12.8 MB
    float* lin     = (float*)alloc(sizeof(float) * N_PANO * HID);         // 25.6 MB
    uint_t* hh     = (uint_t*)alloc(sizeof(uint_t) * N_PANO * 64);        // 12.8 MB
    uint_t* hl     = (uint_t*)alloc(sizeof(uint_t) * N_PANO * 64);        // 12.8 MB
    ushort_t* hstb = (ushort_t*)alloc(sizeof(ushort_t) * N_PANO * OUT_C); // 6.4 MB
    float* es   = (float*)alloc(sizeof(float) * N_PANO);
    float* ed   = (float*)alloc(sizeof(float) * N_PANO);
    float* edt  = (float*)alloc(sizeof(float) * N_FP);
    float* wed0 = (float*)alloc(sizeof(float) * HID);
    float* wed1 = (float*)alloc(sizeof(float) * HID);
    float* wedt = (float*)alloc(sizeof(float) * OUT_C);
    // permuted fragment-order weight buffers (hi/lo)
    ushort_t* s0h = (ushort_t*)alloc(sizeof(ushort_t) * 128 * 128);
    ushort_t* s0l = (ushort_t*)alloc(sizeof(ushort_t) * 128 * 128);
    ushort_t* l0h = (ushort_t*)alloc(sizeof(ushort_t) * 128 * 128);
    ushort_t* l0l = (ushort_t*)alloc(sizeof(ushort_t) * 128 * 128);
    ushort_t* s1h = (ushort_t*)alloc(sizeof(ushort_t) * 128 * 128);
    ushort_t* s1l = (ushort_t*)alloc(sizeof(ushort_t) * 128 * 128);
    ushort_t* l1h = (ushort_t*)alloc(sizeof(ushort_t) * 128 * 128);
    ushort_t* l1l = (ushort_t*)alloc(sizeof(ushort_t) * 128 * 128);
    ushort_t* tsh = (ushort_t*)alloc(sizeof(ushort_t) * 64 * 128);
    ushort_t* tsl = (ushort_t*)alloc(sizeof(ushort_t) * 64 * 128);
    int* cnt    = (int*)alloc(sizeof(int) * N_PANO);
    int* cur    = (int*)alloc(sizeof(int) * N_PANO);
    int* bsum   = (int*)alloc(sizeof(int) * 64);
    int* ptr_pp = (int*)alloc(sizeof(int) * (N_PANO + 1));
    int* col_pp = (int*)alloc(sizeof(int) * E_PP);
    int* ptr_pf = (int*)alloc(sizeof(int) * (N_FP + 1));
    int* col_pf = (int*)alloc(sizeof(int) * E_PF);

    const int* pp_src = edge_pp;
    const int* pp_dst = edge_pp + E_PP;

    // ---- CSR build (pp) ----
    {
        int nb = cdiv(N_PANO, 1024);
        zero_i32<<<cdiv(N_PANO, 256), 256, 0, stream>>>(cnt, N_PANO);
        count_k<<<cdiv(E_PP, 256), 256, 0, stream>>>(pp_dst, E_PP, cnt);
        scan_local<<<nb, 1024, 0, stream>>>(cnt, ptr_pp, bsum, N_PANO);
        scan_bsum<<<1, 64, 0, stream>>>(bsum, nb, &ptr_pp[N_PANO]);
        scan_add<<<nb, 1024, 0, stream>>>(ptr_pp, cur, bsum, N_PANO);
        scatter_k<<<cdiv(E_PP, 256), 256, 0, stream>>>(pp_src, pp_dst, E_PP, cur, col_pp);
    }
    // ---- CSR build (pf) ----
    {
        int nb = cdiv(N_FP, 1024);
        zero_i32<<<cdiv(N_FP, 256), 256, 0, stream>>>(cnt, N_FP);
        count_k<<<cdiv(E_PF, 256), 256, 0, stream>>>(pf_dst, E_PF, cnt);
        scan_local<<<nb, 1024, 0, stream>>>(cnt, ptr_pf, bsum, N_FP);
        scan_bsum<<<1, 64, 0, stream>>>(bsum, nb, &ptr_pf[N_FP]);
        scan_add<<<nb, 1024, 0, stream>>>(ptr_pf, cur, bsum, N_FP);
        scatter_k<<<cdiv(E_PF, 256), 256, 0, stream>>>(pf_src, pf_dst, E_PF, cur, col_pf);
    }
    // ---- fold Wd @ a_d ; convert weights to fragment order ----
    wed_wave<<<HID, 64, 0, stream>>>(Wd0, ad0, wed0, HID);
    wed_wave<<<HID, 64, 0, stream>>>(Wd1, ad1, wed1, HID);
    wed_wave<<<OUT_C, 64, 0, stream>>>(Wtd, atd, wedt, OUT_C);
    wconv<<<288, 256, 0, stream>>>(Ws0, Lw0, Ws1, Lw1, Wts,
                                   s0h, s0l, l0h, l0l, s1h, s1l, l1h, l1l, tsh, tsl);

    const int gemm_grid = cdiv(N_PANO, 128);

    // ---- layer 0 (fp32 input) ----
    gemm_mfma<128, true, true><<<gemm_grid, 256, 0, stream>>>(
        x_pano, nullptr, nullptr, s0h, s0l, l0h, l0l,
        hsb, lin, as0, es, wed0, ed, N_PANO);
    agg_pano4<<<cdiv(N_PANO, 4), 256, 0, stream>>>(ptr_pp, col_pp, es, ed, hsb, lin, b0, Lb0, hh, hl, N_PANO);

    // ---- layer 1 (bf16 hi/lo input) ----
    gemm_mfma<128, true, false><<<gemm_grid, 256, 0, stream>>>(
        nullptr, (const ushort_t*)hh, (const ushort_t*)hl, s1h, s1l, l1h, l1l,
        hsb, lin, as1, es, wed1, ed, N_PANO);
    agg_pano4<<<cdiv(N_PANO, 4), 256, 0, stream>>>(ptr_pp, col_pp, es, ed, hsb, lin, b1, Lb1, hh, hl, N_PANO);

    // ---- translate (pano -> footprint) ----
    gemm_mfma<64, false, false><<<gemm_grid, 256, 0, stream>>>(
        nullptr, (const ushort_t*)hh, (const ushort_t*)hl, tsh, tsl, nullptr, nullptr,
        hstb, nullptr, ats, es, nullptr, nullptr, N_PANO);
    matvec_k<64><<<cdiv(N_FP, 4), 256, 0, stream>>>(x_fp, wedt, edt, N_FP);
    agg_fp3<<<cdiv(N_FP, 4), 256, 0, stream>>>(ptr_pf, col_pf, es, edt, hstb, bt, out, N_FP);
}